// Round 1
// baseline (1244.674 us; speedup 1.0000x reference)
//
#include <hip/hip_runtime.h>

// GATCL: 2-head GAT (N=8192, D=256) + feature conv (K=129) + GAT(D=128) + 2 MLPs + pair dots.
// Strategy: flash-style masked-softmax aggregation with fp16 MFMA (16x16x32),
// fp32 scores/denominators/epilogues. Mask packed to bits (268MB -> 8MB).

typedef _Float16 f16;
typedef _Float16 f16x8 __attribute__((ext_vector_type(8)));
typedef float f32x4 __attribute__((ext_vector_type(4)));

#define DEV __device__ __forceinline__
#define L2E 1.4426950408889634f
#define NN 8192
#define IND 768
#define D1 256
#define DT 512
#define D2 128
#define KC 129
#define EPAIRS 100000

#if __has_builtin(__builtin_amdgcn_exp2f)
#define EXP2(x) __builtin_amdgcn_exp2f(x)
#else
#define EXP2(x) exp2f(x)
#endif

DEV float eluf(float x){ return x > 0.f ? x : EXP2(x*L2E) - 1.f; }

// ---------------- P0: pack adjacency (int32 0/1) into bit mask ----------------
__global__ __launch_bounds__(256) void k_pack(const int* __restrict__ adj, unsigned* __restrict__ maskw){
  int r = blockIdx.x;
  const int* arow = adj + (size_t)r*NN;
  unsigned* mrow = maskw + (size_t)r*(NN/32);
  int lane = threadIdx.x & 63, wv = threadIdx.x >> 6;
  for (int j0 = wv*64; j0 < NN; j0 += 256){
    unsigned long long b = __ballot(arow[j0 + lane] > 0);
    if (lane == 0)  mrow[(j0>>5)]   = (unsigned)b;
    if (lane == 32) mrow[(j0>>5)+1] = (unsigned)(b>>32);
  }
}

// ---------------- P1: cast x to fp16 ----------------
__global__ __launch_bounds__(256) void k_cast_x(const float* __restrict__ x, f16* __restrict__ x16){
  int i = (blockIdx.x*256 + threadIdx.x)*4;
  float4 v = *(const float4*)(x + i);
  union { f16 h[4]; uint2 u; } p;
  p.h[0]=(f16)v.x; p.h[1]=(f16)v.y; p.h[2]=(f16)v.z; p.h[3]=(f16)v.w;
  *(uint2*)(x16 + i) = p.u;
}

// ---------------- P2: W' transpose+cast: Wt[n'=h*256+d][k] = head_W[h][k][d] ----------------
__global__ __launch_bounds__(256) void k_wt(const float* __restrict__ W, f16* __restrict__ Wt){
  int np = blockIdx.x; int h = np >> 8, d = np & 255;
  for (int k = threadIdx.x; k < IND; k += 256)
    Wt[(size_t)np*IND + k] = (f16)W[((size_t)h*IND + k)*D1 + d];
}

// ---------------- G1: h = x @ W' (8192x512), write hT fp16 + wh1/wh2 atomics ----------------
__global__ __launch_bounds__(256) void k_gemm_h(
    const f16* __restrict__ x16, const f16* __restrict__ Wt,
    const float* __restrict__ head_a,
    f16* __restrict__ hT, float* __restrict__ wh1, float* __restrict__ wh2){
  __shared__ f16 As[64*48];
  __shared__ f16 Bs[128*48];
  int m0 = blockIdx.x*64, n0 = blockIdx.y*128;
  int t = threadIdx.x, lane = t & 63, w = t >> 6;
  int wi = w >> 1, wd = w & 1;
  int rm = lane & 15, qm = (lane >> 4)*8;
  f32x4 acc[2][4] = {};
  for (int k0 = 0; k0 < IND; k0 += 32){
    int r = t >> 2, cc = (t & 3)*8;
    *(uint4*)&As[r*48 + cc] = *(const uint4*)&x16[(size_t)(m0 + r)*IND + k0 + cc];
#pragma unroll
    for (int p = 0; p < 2; p++){
      int rb = (t >> 2) + p*64;
      *(uint4*)&Bs[rb*48 + cc] = *(const uint4*)&Wt[(size_t)(n0 + rb)*IND + k0 + cc];
    }
    __syncthreads();
    f16x8 a0 = *(const f16x8*)&As[(wi*32 + rm)*48 + qm];
    f16x8 a1 = *(const f16x8*)&As[(wi*32 + 16 + rm)*48 + qm];
#pragma unroll
    for (int fn = 0; fn < 4; fn++){
      f16x8 b = *(const f16x8*)&Bs[(wd*64 + fn*16 + rm)*48 + qm];
      acc[0][fn] = __builtin_amdgcn_mfma_f32_16x16x32_f16(a0, b, acc[0][fn], 0, 0, 0);
      acc[1][fn] = __builtin_amdgcn_mfma_f32_16x16x32_f16(a1, b, acc[1][fn], 0, 0, 0);
    }
    __syncthreads();
  }
  int quad = lane >> 4, cl = lane & 15;
  int head = n0 >> 8;
  float a1v[4], a2v[4];
#pragma unroll
  for (int fn = 0; fn < 4; fn++){
    int d = (n0 & 255) + wd*64 + fn*16 + cl;
    a1v[fn] = head_a[head*DT + d];
    a2v[fn] = head_a[head*DT + D1 + d];
  }
  float p1[2][4], p2[2][4];
#pragma unroll
  for (int fi = 0; fi < 2; fi++){
#pragma unroll
    for (int fn = 0; fn < 4; fn++){
      int npg = n0 + wd*64 + fn*16 + cl;
      int mg = m0 + wi*32 + fi*16 + quad*4;
      union { f16 h[4]; uint2 u; } pk;
#pragma unroll
      for (int reg = 0; reg < 4; reg++) pk.h[reg] = (f16)acc[fi][fn][reg];
      *(uint2*)&hT[(size_t)npg*NN + mg] = pk.u;
    }
#pragma unroll
    for (int reg = 0; reg < 4; reg++){
      float s1 = 0.f, s2 = 0.f;
#pragma unroll
      for (int fn = 0; fn < 4; fn++){ s1 += acc[fi][fn][reg]*a1v[fn]; s2 += acc[fi][fn][reg]*a2v[fn]; }
      p1[fi][reg] = s1; p2[fi][reg] = s2;
    }
  }
#pragma unroll
  for (int o = 1; o < 16; o <<= 1){
#pragma unroll
    for (int fi = 0; fi < 2; fi++)
#pragma unroll
      for (int reg = 0; reg < 4; reg++){
        p1[fi][reg] += __shfl_xor(p1[fi][reg], o);
        p2[fi][reg] += __shfl_xor(p2[fi][reg], o);
      }
  }
  if (cl == 0){
#pragma unroll
    for (int fi = 0; fi < 2; fi++)
#pragma unroll
      for (int reg = 0; reg < 4; reg++){
        int mg = m0 + wi*32 + fi*16 + quad*4 + reg;
        atomicAdd(&wh1[head*NN + mg], p1[fi][reg]);
        atomicAdd(&wh2[head*NN + mg], p2[fi][reg]);
      }
  }
}

// ---------------- P4a: global max of wh2 per head (sortable-uint encoding) ----------------
__global__ __launch_bounds__(256) void k_gmax(const float* __restrict__ wh2, unsigned* __restrict__ gmax){
  int h = blockIdx.y;
  int i = blockIdx.x*256 + threadIdx.x;
  float v = wh2[h*NN + i];
#pragma unroll
  for (int o = 32; o > 0; o >>= 1) v = fmaxf(v, __shfl_xor(v, o));
  if ((threadIdx.x & 63) == 0){
    unsigned b = __float_as_uint(v);
    unsigned enc = (b & 0x80000000u) ? ~b : (b | 0x80000000u);
    atomicMax(gmax + h, enc);
  }
}

// ---------------- P4b: column terms c1 = wh2*L2E, c2 = 0.2*wh2*L2E ----------------
__global__ __launch_bounds__(256) void k_colterms(const float* __restrict__ wh2,
                                                  float* __restrict__ c1, float* __restrict__ c2){
  int i = blockIdx.x*256 + threadIdx.x;   // 2*8192
  float v = wh2[i]*L2E;
  c1[i] = v; c2[i] = 0.2f*v;
}

// ---------------- A1: head GAT aggregation (leaky_relu scores) ----------------
__global__ __launch_bounds__(256) void k_agg_head(
    const f16* __restrict__ hT, const unsigned* __restrict__ maskw,
    const float* __restrict__ wh1, const float* __restrict__ c1,
    const float* __restrict__ c2, const unsigned* __restrict__ gmaxp,
    float* __restrict__ num, float* __restrict__ den){
  __shared__ f16 Hs[128*48];
  __shared__ f16 Ws[64*48];
  __shared__ float rowa[64], rowb[64], denl[64];
  __shared__ float cc1[32], cc2[32];
  __shared__ unsigned mrow[64];
  int head = blockIdx.z;
  int i0 = blockIdx.x*64, d0 = blockIdx.y*128;
  const f16* hTh = hT + ((size_t)head*D1 + d0)*NN;
  int t = threadIdx.x, lane = t & 63, w = t >> 6;
  int wi = w >> 1, wd = w & 1;
  int rm = lane & 15, qm = (lane >> 4)*8;
  if (t < 64){
    unsigned e = gmaxp[head];
    float gmax = __uint_as_float((e & 0x80000000u) ? (e ^ 0x80000000u) : ~e);
    float u = wh1[head*NN + i0 + t];
    float sm = u + gmax;
    float M = (sm > 0.f ? sm : 0.2f*sm)*L2E;   // leaky(wh1+gmax) in log2 units
    rowa[t] = u*L2E - M;
    rowb[t] = 0.2f*u*L2E - M;
    denl[t] = 0.f;
  }
  const float* c1h = c1 + head*NN;
  const float* c2h = c2 + head*NN;
  int si = t >> 2, sj = (t & 3)*8;
  f32x4 acc[2][4] = {};
  for (int j0 = 0; j0 < NN; j0 += 32){
    int cc = (t & 3)*8;
#pragma unroll
    for (int p = 0; p < 2; p++){
      int rb = (t >> 2) + p*64;
      *(uint4*)&Hs[rb*48 + cc] = *(const uint4*)&hTh[(size_t)rb*NN + j0 + cc];
    }
    if (t < 64) mrow[t] = maskw[(size_t)(i0 + t)*(NN/32) + (j0 >> 5)];
    else if (t < 96)  cc1[t - 64] = c1h[j0 + (t - 64)];
    else if (t < 128) cc2[t - 96] = c2h[j0 + (t - 96)];
    __syncthreads();
    float ra = rowa[si], rb2 = rowb[si];
    unsigned mb = mrow[si] >> sj;
    float dsum = 0.f;
    f16x8 wloc;
#pragma unroll
    for (int q = 0; q < 8; q++){
      float s1 = ra + cc1[sj + q];
      float s2 = rb2 + cc2[sj + q];
      float wv = EXP2(fmaxf(s1, s2));          // exp(leaky(s)-m), <= 1
      wv = ((mb >> q) & 1u) ? wv : 0.f;
      dsum += wv;
      wloc[q] = (f16)wv;
    }
    dsum += __shfl_xor(dsum, 1);
    dsum += __shfl_xor(dsum, 2);
    if ((t & 3) == 0) denl[si] += dsum;
    *(f16x8*)&Ws[si*48 + sj] = wloc;
    __syncthreads();
    f16x8 a0 = *(const f16x8*)&Ws[(wi*32 + rm)*48 + qm];
    f16x8 a1 = *(const f16x8*)&Ws[(wi*32 + 16 + rm)*48 + qm];
#pragma unroll
    for (int fn = 0; fn < 4; fn++){
      f16x8 b = *(const f16x8*)&Hs[(wd*64 + fn*16 + rm)*48 + qm];
      acc[0][fn] = __builtin_amdgcn_mfma_f32_16x16x32_f16(a0, b, acc[0][fn], 0, 0, 0);
      acc[1][fn] = __builtin_amdgcn_mfma_f32_16x16x32_f16(a1, b, acc[1][fn], 0, 0, 0);
    }
    __syncthreads();
  }
  int quad = lane >> 4, cl = lane & 15;
#pragma unroll
  for (int fi = 0; fi < 2; fi++)
#pragma unroll
    for (int fn = 0; fn < 4; fn++){
      int rr = i0 + wi*32 + fi*16 + quad*4;
      int ccg = d0 + wd*64 + fn*16 + cl;
#pragma unroll
      for (int reg = 0; reg < 4; reg++)
        num[((size_t)head*NN + rr + reg)*D1 + ccg] = acc[fi][fn][reg];
    }
  if (blockIdx.y == 0 && t < 64) den[head*NN + i0 + t] = denl[t];
}

// ---------------- E1: merge heads -> z -> conv -> gT(fp16) + whc1L/whc2L ----------------
__global__ __launch_bounds__(256) void k_merge_conv(
    const float* __restrict__ num, const float* __restrict__ den,
    const float* __restrict__ head_b, const float* __restrict__ conv_w,
    const float* __restrict__ conv_cb, const float* __restrict__ conv_a,
    f16* __restrict__ gT, float* __restrict__ wc1L, float* __restrict__ wc2L){
  __shared__ float zrow[2][256];
  __shared__ float cw[KC];
  __shared__ float ca[256];
  __shared__ float red[2][2];
  __shared__ float red2[2][2][2];
  int t = threadIdx.x, g = t >> 7, c = t & 127;
  int r = blockIdx.x*2 + g;
  if (t < KC) cw[t] = conv_w[t];
  ca[t] = conv_a[t];
  float zv0 = 0.f, zv1 = 0.f;
#pragma unroll
  for (int h = 0; h < 2; h++){
    const float* nr = num + ((size_t)h*NN + r)*D1;
    float inv = 1.f / den[h*NN + r];
    float e0 = eluf(nr[c]*inv);
    float e1 = eluf(nr[c + 128]*inv);
    float ss = e0*e0 + e1*e1;
#pragma unroll
    for (int o = 32; o > 0; o >>= 1) ss += __shfl_xor(ss, o);
    if ((t & 63) == 0) red[g][(t >> 6) & 1] = ss;
    __syncthreads();
    float invn = 1.f / fmaxf(sqrtf(red[g][0] + red[g][1]), 1e-12f);
    zv0 += e0*invn + head_b[h*D1 + c];
    zv1 += e1*invn + head_b[h*D1 + 128 + c];
    __syncthreads();
  }
  zrow[g][c]       = eluf(0.5f*zv0);
  zrow[g][c + 128] = eluf(0.5f*zv1);
  __syncthreads();
  float s = conv_cb[0];
  for (int k = 0; k < KC; k++) s += zrow[g][c + k]*cw[k];
  gT[(size_t)c*NN + r] = (f16)s;
  float p1 = s*ca[c], p2 = s*ca[128 + c];
#pragma unroll
  for (int o = 32; o > 0; o >>= 1){ p1 += __shfl_xor(p1, o); p2 += __shfl_xor(p2, o); }
  if ((t & 63) == 0){ red2[g][(t >> 6) & 1][0] = p1; red2[g][(t >> 6) & 1][1] = p2; }
  __syncthreads();
  if ((t & 127) == 0){
    wc1L[r] = (red2[g][0][0] + red2[g][1][0])*L2E;
    wc2L[r] = (red2[g][0][1] + red2[g][1][1])*L2E;
  }
}

// ---------------- A2: conv GAT aggregation (elu scores, m=0) ----------------
__global__ __launch_bounds__(256) void k_agg_conv(
    const f16* __restrict__ gT, const unsigned* __restrict__ maskw,
    const float* __restrict__ wc1L, const float* __restrict__ wc2L,
    float* __restrict__ num, float* __restrict__ den){
  __shared__ f16 Hs[128*48];
  __shared__ f16 Ws[64*48];
  __shared__ float rowc[64], denl[64];
  __shared__ float cc1[32];
  __shared__ unsigned mrow[64];
  int i0 = blockIdx.x*64;
  int t = threadIdx.x, lane = t & 63, w = t >> 6;
  int wi = w >> 1, wd = w & 1;
  int rm = lane & 15, qm = (lane >> 4)*8;
  if (t < 64){ rowc[t] = wc1L[i0 + t]; denl[t] = 0.f; }
  int si = t >> 2, sj = (t & 3)*8;
  f32x4 acc[2][4] = {};
  for (int j0 = 0; j0 < NN; j0 += 32){
    int cc = (t & 3)*8;
#pragma unroll
    for (int p = 0; p < 2; p++){
      int rb = (t >> 2) + p*64;
      *(uint4*)&Hs[rb*48 + cc] = *(const uint4*)&gT[(size_t)rb*NN + j0 + cc];
    }
    if (t < 64) mrow[t] = maskw[(size_t)(i0 + t)*(NN/32) + (j0 >> 5)];
    else if (t < 96) cc1[t - 64] = wc2L[j0 + (t - 64)];
    __syncthreads();
    float ra = rowc[si];
    unsigned mb = mrow[si] >> sj;
    float dsum = 0.f;
    f16x8 wloc;
#pragma unroll
    for (int q = 0; q < 8; q++){
      float sL = ra + cc1[sj + q];            // (whc1+whc2)*log2e
      float t2 = EXP2(sL);                    // e^s
      float wv = sL > 0.f ? t2 : EXP2((t2 - 1.f)*L2E);  // exp(elu(s))
      wv = ((mb >> q) & 1u) ? wv : 0.f;
      dsum += wv;
      wloc[q] = (f16)wv;
    }
    dsum += __shfl_xor(dsum, 1);
    dsum += __shfl_xor(dsum, 2);
    if ((t & 3) == 0) denl[si] += dsum;
    *(f16x8*)&Ws[si*48 + sj] = wloc;
    __syncthreads();
    f16x8 a0 = *(const f16x8*)&Ws[(wi*32 + rm)*48 + qm];
    f16x8 a1 = *(const f16x8*)&Ws[(wi*32 + 16 + rm)*48 + qm];
#pragma unroll
    for (int fn = 0; fn < 4; fn++){
      f16x8 b = *(const f16x8*)&Hs[(wd*64 + fn*16 + rm)*48 + qm];
      acc[0][fn] = __builtin_amdgcn_mfma_f32_16x16x32_f16(a0, b, acc[0][fn], 0, 0, 0);
      acc[1][fn] = __builtin_amdgcn_mfma_f32_16x16x32_f16(a1, b, acc[1][fn], 0, 0, 0);
    }
    __syncthreads();
  }
  int quad = lane >> 4, cl = lane & 15;
#pragma unroll
  for (int fi = 0; fi < 2; fi++)
#pragma unroll
    for (int fn = 0; fn < 4; fn++){
      int rr = i0 + wi*32 + fi*16 + quad*4;
      int ccg = wd*64 + fn*16 + cl;
#pragma unroll
      for (int reg = 0; reg < 4; reg++)
        num[(size_t)(rr + reg)*D2 + ccg] = acc[fi][fn][reg];
    }
  if (t < 64) den[i0 + t] = denl[t];
}

// ---------------- E2: embed = l2norm(elu(num/den)) + conv_b ----------------
__global__ __launch_bounds__(256) void k_embed(
    const float* __restrict__ numc, const float* __restrict__ denc,
    const float* __restrict__ conv_b, float* __restrict__ embed){
  __shared__ float red[2][2];
  int t = threadIdx.x, g = t >> 7, c = t & 127;
  int r = blockIdx.x*2 + g;
  float e = eluf(numc[(size_t)r*D2 + c] / denc[r]);
  float ss = e*e;
#pragma unroll
  for (int o = 32; o > 0; o >>= 1) ss += __shfl_xor(ss, o);
  if ((t & 63) == 0) red[g][(t >> 6) & 1] = ss;
  __syncthreads();
  float invn = 1.f / fmaxf(sqrtf(red[g][0] + red[g][1]), 1e-12f);
  embed[(size_t)r*D2 + c] = e*invn + conv_b[c];
}

// ---------------- E3: two 128->128->64 elu MLPs (weights in registers) ----------------
__global__ __launch_bounds__(256) void k_mlp(
    const float* __restrict__ embed,
    const float* __restrict__ fw1, const float* __restrict__ fb1,
    const float* __restrict__ fw2, const float* __restrict__ fb2,
    const float* __restrict__ gw1, const float* __restrict__ gb1,
    const float* __restrict__ gw2, const float* __restrict__ gb2,
    float* __restrict__ tf, float* __restrict__ tg){
  const float* w1 = blockIdx.y ? gw1 : fw1;
  const float* b1 = blockIdx.y ? gb1 : fb1;
  const float* w2 = blockIdx.y ? gw2 : fw2;
  const float* b2 = blockIdx.y ? gb2 : fb2;
  float* out = blockIdx.y ? tg : tf;
  int t = threadIdx.x;
  int c = t & 127, kh = t >> 7;
  int o = t & 63, kh2 = t >> 6;
  float rw1[64];
#pragma unroll
  for (int i = 0; i < 64; i++) rw1[i] = w1[(kh*64 + i)*128 + c];
  float rw2[32];
#pragma unroll
  for (int i = 0; i < 32; i++) rw2[i] = w2[(kh2*32 + i)*64 + o];
  __shared__ float erow[2][128];
  __shared__ float hidp[2][2][128];
  __shared__ float hid[2][128];
  __shared__ float outp[4][2][64];
  int r0 = blockIdx.x*128;
  for (int it = 0; it < 64; it++){
    int rbase = r0 + it*2;
    erow[t >> 7][t & 127] = embed[(size_t)(rbase + (t >> 7))*128 + (t & 127)];
    __syncthreads();
#pragma unroll
    for (int g = 0; g < 2; g++){
      float s = 0.f;
#pragma unroll
      for (int i = 0; i < 64; i++) s += erow[g][kh*64 + i]*rw1[i];
      hidp[kh][g][c] = s;
    }
    __syncthreads();
    { int gg = t >> 7, ccx = t & 127;
      hid[gg][ccx] = eluf(b1[ccx] + hidp[0][gg][ccx] + hidp[1][gg][ccx]); }
    __syncthreads();
#pragma unroll
    for (int g = 0; g < 2; g++){
      float s = 0.f;
#pragma unroll
      for (int i = 0; i < 32; i++) s += hid[g][kh2*32 + i]*rw2[i];
      outp[kh2][g][o] = s;
    }
    __syncthreads();
    if (t < 128){
      int gg = t >> 6, oo = t & 63;
      out[(size_t)(rbase + gg)*64 + oo] =
        eluf(b2[oo] + outp[0][gg][oo] + outp[1][gg][oo] + outp[2][gg][oo] + outp[3][gg][oo]);
    }
    __syncthreads();
  }
}

// ---------------- E4: pred = rowwise dot of gathered tf/tg ----------------
__global__ __launch_bounds__(256) void k_pred(
    const int* __restrict__ ts, const float* __restrict__ tf,
    const float* __restrict__ tg, float* __restrict__ out){
  int p = blockIdx.x*4 + (threadIdx.x >> 6);
  int lane = threadIdx.x & 63;
  if (p >= EPAIRS) return;
  int i = ts[2*p], j = ts[2*p + 1];
  float v = tf[(size_t)i*64 + lane]*tg[(size_t)j*64 + lane];
#pragma unroll
  for (int o = 32; o > 0; o >>= 1) v += __shfl_xor(v, o);
  if (lane == 0) out[p] = v;
}

// ---------------- workspace layout ----------------
#define OFF_MASK  ((size_t)0)
#define OFF_X16   ((size_t)8388608)
#define OFF_WT16  ((size_t)20971520)
#define OFF_HT16  ((size_t)21757952)
#define OFF_WH1   ((size_t)30146560)
#define OFF_WH2   ((size_t)30212096)
#define OFF_C1    ((size_t)30277632)
#define OFF_C2    ((size_t)30343168)
#define OFF_GMAX  ((size_t)30408704)
#define OFF_NUM1  ((size_t)30408960)
#define OFF_DEN1  ((size_t)47186176)
#define OFF_GT16  ((size_t)47251712)
#define OFF_WC1L  ((size_t)49348864)
#define OFF_WC2L  ((size_t)49381632)
#define OFF_NUMC  ((size_t)49414400)
#define OFF_DENC  ((size_t)53608704)
#define OFF_EMB   ((size_t)53641472)
#define OFF_TF    ((size_t)57835776)
#define OFF_TG    ((size_t)59932928)

extern "C" void kernel_launch(void* const* d_in, const int* in_sizes, int n_in,
                              void* d_out, int out_size, void* d_ws, size_t ws_size,
                              hipStream_t stream){
  const float* x      = (const float*)d_in[0];
  const int*   adj    = (const int*)d_in[1];
  const int*   ts     = (const int*)d_in[2];
  const float* head_W = (const float*)d_in[3];
  const float* head_a = (const float*)d_in[4];
  const float* head_b = (const float*)d_in[5];
  const float* conv_w = (const float*)d_in[6];
  const float* conv_cb= (const float*)d_in[7];
  const float* conv_a = (const float*)d_in[8];
  const float* conv_b = (const float*)d_in[9];
  const float* tf_w1  = (const float*)d_in[10];
  const float* tf_b1  = (const float*)d_in[11];
  const float* tf_w2  = (const float*)d_in[12];
  const float* tf_b2  = (const float*)d_in[13];
  const float* tg_w1  = (const float*)d_in[14];
  const float* tg_b1  = (const float*)d_in[15];
  const float* tg_w2  = (const float*)d_in[16];
  const float* tg_b2  = (const float*)d_in[17];
  float* outp = (float*)d_out;
  char* ws = (char*)d_ws;

  unsigned* maskw = (unsigned*)(ws + OFF_MASK);
  f16*   x16   = (f16*)(ws + OFF_X16);
  f16*   Wt16  = (f16*)(ws + OFF_WT16);
  f16*   hT16  = (f16*)(ws + OFF_HT16);
  float* wh1   = (float*)(ws + OFF_WH1);
  float* wh2   = (float*)(ws + OFF_WH2);
  float* c1    = (float*)(ws + OFF_C1);
  float* c2    = (float*)(ws + OFF_C2);
  unsigned* gmax = (unsigned*)(ws + OFF_GMAX);
  float* num1  = (float*)(ws + OFF_NUM1);
  float* den1  = (float*)(ws + OFF_DEN1);
  f16*   gT16  = (f16*)(ws + OFF_GT16);
  float* wc1L  = (float*)(ws + OFF_WC1L);
  float* wc2L  = (float*)(ws + OFF_WC2L);
  float* numc  = (float*)(ws + OFF_NUMC);
  float* denc  = (float*)(ws + OFF_DENC);
  float* emb   = (float*)(ws + OFF_EMB);
  float* tf    = (float*)(ws + OFF_TF);
  float* tg    = (float*)(ws + OFF_TG);

  // zero atomic accumulators (ws is poisoned before every call)
  hipMemsetAsync(wh1, 0, 2*2*NN*sizeof(float), stream);   // wh1+wh2 (contiguous)
  hipMemsetAsync(gmax, 0, 2*sizeof(unsigned), stream);

  k_pack   <<<NN, 256, 0, stream>>>(adj, maskw);
  k_cast_x <<<(NN*IND)/(256*4), 256, 0, stream>>>(x, x16);
  k_wt     <<<DT, 256, 0, stream>>>(head_W, Wt16);
  k_gemm_h <<<dim3(NN/64, DT/128), 256, 0, stream>>>(x16, Wt16, head_a, hT16, wh1, wh2);
  k_gmax   <<<dim3(NN/256, 2), 256, 0, stream>>>(wh2, gmax);
  k_colterms<<<(2*NN)/256, 256, 0, stream>>>(wh2, c1, c2);
  k_agg_head<<<dim3(NN/64, 2, 2), 256, 0, stream>>>(hT16, maskw, wh1, c1, c2, gmax, num1, den1);
  k_merge_conv<<<NN/2, 256, 0, stream>>>(num1, den1, head_b, conv_w, conv_cb, conv_a, gT16, wc1L, wc2L);
  k_agg_conv<<<NN/64, 256, 0, stream>>>(gT16, maskw, wc1L, wc2L, numc, denc);
  k_embed  <<<NN/2, 256, 0, stream>>>(numc, denc, conv_b, emb);
  k_mlp    <<<dim3(64, 2), 256, 0, stream>>>(emb, tf_w1, tf_b1, tf_w2, tf_b2,
                                             tg_w1, tg_b1, tg_w2, tg_b2, tf, tg);
  k_pred   <<<EPAIRS/4, 256, 0, stream>>>(ts, tf, tg, outp);
}

// Round 2
// 710.390 us; speedup vs baseline: 1.7521x; 1.7521x over previous
//
#include <hip/hip_runtime.h>

// GATCL: 2-head GAT (N=8192, D=256) + feature conv (K=129) + GAT(D=128) + 2 MLPs + pair dots.
// R2: flash aggregation with j-tile 64, full-D blocks, 2 barriers/iter, stride-72 LDS,
// j-split parallelism with atomicAdd merge. fp16 MFMA 16x16x32, fp32 everything else.

typedef _Float16 f16;
typedef _Float16 f16x8 __attribute__((ext_vector_type(8)));
typedef float f32x4 __attribute__((ext_vector_type(4)));

#define DEV __device__ __forceinline__
#define L2E 1.4426950408889634f
#define NN 8192
#define IND 768
#define D1 256
#define DT 512
#define D2 128
#define KC 129
#define EPAIRS 100000

#if __has_builtin(__builtin_amdgcn_exp2f)
#define EXP2(x) __builtin_amdgcn_exp2f(x)
#else
#define EXP2(x) exp2f(x)
#endif

DEV float eluf(float x){ return x > 0.f ? x : EXP2(x*L2E) - 1.f; }

// ---------------- P0: pack adjacency (int32 0/1) into bit mask, int4 loads ----------------
__global__ __launch_bounds__(256) void k_pack(const int4* __restrict__ adj4, unsigned* __restrict__ maskw){
  int idx = blockIdx.x*256 + threadIdx.x;          // int4 index; j-flat = 4*idx
  int4 v = adj4[idx];
  unsigned n = (unsigned)(v.x > 0) | ((unsigned)(v.y > 0) << 1)
             | ((unsigned)(v.z > 0) << 2) | ((unsigned)(v.w > 0) << 3);
  n |= __shfl_xor(n, 1) << 4;    // lanes ≡0 mod 2 now hold a correct byte
  n |= __shfl_xor(n, 2) << 8;    // lanes ≡0 mod 4 hold correct 16 bits
  n |= __shfl_xor(n, 4) << 16;   // lanes ≡0 mod 8 hold correct 32 bits
  if ((threadIdx.x & 7) == 0) maskw[idx >> 3] = n;
}

// ---------------- P1: cast x to fp16 ----------------
__global__ __launch_bounds__(256) void k_cast_x(const float* __restrict__ x, f16* __restrict__ x16){
  int i = (blockIdx.x*256 + threadIdx.x)*4;
  float4 v = *(const float4*)(x + i);
  union { f16 h[4]; uint2 u; } p;
  p.h[0]=(f16)v.x; p.h[1]=(f16)v.y; p.h[2]=(f16)v.z; p.h[3]=(f16)v.w;
  *(uint2*)(x16 + i) = p.u;
}

// ---------------- P2: W' transpose+cast: Wt[n'=h*256+d][k] = head_W[h][k][d] ----------------
__global__ __launch_bounds__(256) void k_wt(const float* __restrict__ W, f16* __restrict__ Wt){
  int np = blockIdx.x; int h = np >> 8, d = np & 255;
  for (int k = threadIdx.x; k < IND; k += 256)
    Wt[(size_t)np*IND + k] = (f16)W[((size_t)h*IND + k)*D1 + d];
}

// ---------------- G1: h = x @ W' (8192x512), BK=64, write hT fp16 + wh1/wh2 atomics ----------------
__global__ __launch_bounds__(256) void k_gemm_h(
    const f16* __restrict__ x16, const f16* __restrict__ Wt,
    const float* __restrict__ head_a,
    f16* __restrict__ hT, float* __restrict__ wh1, float* __restrict__ wh2){
  __shared__ f16 As[64*72];
  __shared__ f16 Bs[128*72];
  int m0 = blockIdx.x*64, n0 = blockIdx.y*128;
  int t = threadIdx.x, lane = t & 63, w = t >> 6;
  int wi = w >> 1, wd = w & 1;
  int rm = lane & 15, qm = (lane >> 4)*8;
  f32x4 acc[2][4] = {};
  for (int k0 = 0; k0 < IND; k0 += 64){
#pragma unroll
    for (int p = 0; p < 2; p++){
      int idx = p*256 + t, r = idx >> 3, cc = (idx & 7)*8;
      *(uint4*)&As[r*72 + cc] = *(const uint4*)&x16[(size_t)(m0 + r)*IND + k0 + cc];
    }
#pragma unroll
    for (int p = 0; p < 4; p++){
      int idx = p*256 + t, r = idx >> 3, cc = (idx & 7)*8;
      *(uint4*)&Bs[r*72 + cc] = *(const uint4*)&Wt[(size_t)(n0 + r)*IND + k0 + cc];
    }
    __syncthreads();
#pragma unroll
    for (int ks = 0; ks < 2; ks++){
      f16x8 a0 = *(const f16x8*)&As[(wi*32 + rm)*72 + ks*32 + qm];
      f16x8 a1 = *(const f16x8*)&As[(wi*32 + 16 + rm)*72 + ks*32 + qm];
#pragma unroll
      for (int fn = 0; fn < 4; fn++){
        f16x8 b = *(const f16x8*)&Bs[(wd*64 + fn*16 + rm)*72 + ks*32 + qm];
        acc[0][fn] = __builtin_amdgcn_mfma_f32_16x16x32_f16(a0, b, acc[0][fn], 0, 0, 0);
        acc[1][fn] = __builtin_amdgcn_mfma_f32_16x16x32_f16(a1, b, acc[1][fn], 0, 0, 0);
      }
    }
    __syncthreads();
  }
  int quad = lane >> 4, cl = lane & 15;
  int head = n0 >> 8;
  float a1v[4], a2v[4];
#pragma unroll
  for (int fn = 0; fn < 4; fn++){
    int d = (n0 & 255) + wd*64 + fn*16 + cl;
    a1v[fn] = head_a[head*DT + d];
    a2v[fn] = head_a[head*DT + D1 + d];
  }
  float p1[2][4], p2[2][4];
#pragma unroll
  for (int fi = 0; fi < 2; fi++){
#pragma unroll
    for (int fn = 0; fn < 4; fn++){
      int npg = n0 + wd*64 + fn*16 + cl;
      int mg = m0 + wi*32 + fi*16 + quad*4;
      union { f16 h[4]; uint2 u; } pk;
#pragma unroll
      for (int reg = 0; reg < 4; reg++) pk.h[reg] = (f16)acc[fi][fn][reg];
      *(uint2*)&hT[(size_t)npg*NN + mg] = pk.u;
    }
#pragma unroll
    for (int reg = 0; reg < 4; reg++){
      float s1 = 0.f, s2 = 0.f;
#pragma unroll
      for (int fn = 0; fn < 4; fn++){ s1 += acc[fi][fn][reg]*a1v[fn]; s2 += acc[fi][fn][reg]*a2v[fn]; }
      p1[fi][reg] = s1; p2[fi][reg] = s2;
    }
  }
#pragma unroll
  for (int o = 1; o < 16; o <<= 1){
#pragma unroll
    for (int fi = 0; fi < 2; fi++)
#pragma unroll
      for (int reg = 0; reg < 4; reg++){
        p1[fi][reg] += __shfl_xor(p1[fi][reg], o);
        p2[fi][reg] += __shfl_xor(p2[fi][reg], o);
      }
  }
  if (cl == 0){
#pragma unroll
    for (int fi = 0; fi < 2; fi++)
#pragma unroll
      for (int reg = 0; reg < 4; reg++){
        int mg = m0 + wi*32 + fi*16 + quad*4 + reg;
        atomicAdd(&wh1[head*NN + mg], p1[fi][reg]);
        atomicAdd(&wh2[head*NN + mg], p2[fi][reg]);
      }
  }
}

// ---------------- P4a: global max of wh2 per head ----------------
__global__ __launch_bounds__(256) void k_gmax(const float* __restrict__ wh2, unsigned* __restrict__ gmax){
  int h = blockIdx.y;
  int i = blockIdx.x*256 + threadIdx.x;
  float v = wh2[h*NN + i];
#pragma unroll
  for (int o = 32; o > 0; o >>= 1) v = fmaxf(v, __shfl_xor(v, o));
  if ((threadIdx.x & 63) == 0){
    unsigned b = __float_as_uint(v);
    unsigned enc = (b & 0x80000000u) ? ~b : (b | 0x80000000u);
    atomicMax(gmax + h, enc);
  }
}

// ---------------- P4b: column terms c1 = wh2*L2E, c2 = 0.2*wh2*L2E ----------------
__global__ __launch_bounds__(256) void k_colterms(const float* __restrict__ wh2,
                                                  float* __restrict__ c1, float* __restrict__ c2){
  int i = blockIdx.x*256 + threadIdx.x;
  float v = wh2[i]*L2E;
  c1[i] = v; c2[i] = 0.2f*v;
}

// ---------------- A1: head GAT aggregation. i-tile 64, full D=256, j-split 2 ----------------
__global__ __launch_bounds__(256) void k_agg_head(
    const f16* __restrict__ hT, const unsigned* __restrict__ maskw,
    const float* __restrict__ wh1, const float* __restrict__ c1,
    const float* __restrict__ c2, const unsigned* __restrict__ gmaxp,
    float* __restrict__ num, float* __restrict__ den){
  __shared__ f16 Hs[256*72];
  __shared__ f16 Ws[64*72];
  __shared__ float rowa[64], rowb[64];
  int head = blockIdx.z;
  int i0 = blockIdx.x*64;
  int jbase = blockIdx.y*4096;
  const f16* hTh = hT + (size_t)head*D1*NN;
  int t = threadIdx.x, lane = t & 63, w = t >> 6;
  int rm = lane & 15, qm = (lane >> 4)*8;
  if (t < 64){
    unsigned e = gmaxp[head];
    float gmax = __uint_as_float((e & 0x80000000u) ? (e ^ 0x80000000u) : ~e);
    float u = wh1[head*NN + i0 + t];
    float sm = u + gmax;
    float M = (sm > 0.f ? sm : 0.2f*sm)*L2E;   // leaky(wh1+gmax) in log2 units
    rowa[t] = u*L2E - M;
    rowb[t] = 0.2f*u*L2E - M;
  }
  __syncthreads();
  int si = t >> 2, sjq = (t & 3)*16;
  float ra = rowa[si], rb = rowb[si];
  const float* c1h = c1 + head*NN;
  const float* c2h = c2 + head*NN;
  const unsigned* mrowp = maskw + (size_t)(i0 + si)*(NN/32);
  float rden = 0.f;
  f32x4 acc[4][4] = {};
  for (int j0 = 0; j0 < 4096; j0 += 64){
    int jg = jbase + j0;
    // stage Hs[d=256][j=64] (global->reg->LDS)
#pragma unroll
    for (int p = 0; p < 8; p++){
      int idx = p*256 + t, dr = idx >> 3, cc = (idx & 7)*8;
      *(uint4*)&Hs[dr*72 + cc] = *(const uint4*)&hTh[(size_t)dr*NN + jg + cc];
    }
    // scores: direct global reads (L1-resident), no staging dependency
    unsigned mb = mrowp[(jg + sjq) >> 5] >> (sjq & 31);
    float ca[16], cb[16];
#pragma unroll
    for (int k = 0; k < 4; k++){
      float4 va = *(const float4*)&c1h[jg + sjq + 4*k];
      float4 vb = *(const float4*)&c2h[jg + sjq + 4*k];
      ca[4*k]=va.x; ca[4*k+1]=va.y; ca[4*k+2]=va.z; ca[4*k+3]=va.w;
      cb[4*k]=vb.x; cb[4*k+1]=vb.y; cb[4*k+2]=vb.z; cb[4*k+3]=vb.w;
    }
    f16x8 wlo, whi;
    float dsum = 0.f;
#pragma unroll
    for (int q = 0; q < 16; q++){
      float s1 = ra + ca[q], s2 = rb + cb[q];
      float wv = EXP2(fmaxf(s1, s2));          // exp(leaky(s)-m) <= 1
      wv = ((mb >> q) & 1u) ? wv : 0.f;
      dsum += wv;
      if (q < 8) wlo[q] = (f16)wv; else whi[q - 8] = (f16)wv;
    }
    *(f16x8*)&Ws[si*72 + sjq]     = wlo;
    *(f16x8*)&Ws[si*72 + sjq + 8] = whi;
    dsum += __shfl_xor(dsum, 1);
    dsum += __shfl_xor(dsum, 2);
    rden += dsum;
    __syncthreads();
    // MFMA: wave w owns d-range w*64..w*64+63, all 64 i
#pragma unroll
    for (int ks = 0; ks < 2; ks++){
      f16x8 a[4], b[4];
#pragma unroll
      for (int mi = 0; mi < 4; mi++) a[mi] = *(const f16x8*)&Ws[(mi*16 + rm)*72 + ks*32 + qm];
#pragma unroll
      for (int fn = 0; fn < 4; fn++) b[fn] = *(const f16x8*)&Hs[(w*64 + fn*16 + rm)*72 + ks*32 + qm];
#pragma unroll
      for (int mi = 0; mi < 4; mi++)
#pragma unroll
        for (int fn = 0; fn < 4; fn++)
          acc[mi][fn] = __builtin_amdgcn_mfma_f32_16x16x32_f16(a[mi], b[fn], acc[mi][fn], 0, 0, 0);
    }
    __syncthreads();
  }
  if ((t & 3) == 0) atomicAdd(&den[head*NN + i0 + si], rden);
  int quad = lane >> 4, cl = lane & 15;
#pragma unroll
  for (int mi = 0; mi < 4; mi++)
#pragma unroll
    for (int fn = 0; fn < 4; fn++){
      int rr = i0 + mi*16 + quad*4;
      int dc = w*64 + fn*16 + cl;
#pragma unroll
      for (int reg = 0; reg < 4; reg++)
        atomicAdd(&num[((size_t)head*NN + rr + reg)*D1 + dc], acc[mi][fn][reg]);
    }
}

// ---------------- E1: merge heads -> z -> conv -> gT(fp16) + wc1L/wc2L ----------------
__global__ __launch_bounds__(256) void k_merge_conv(
    const float* __restrict__ num, const float* __restrict__ den,
    const float* __restrict__ head_b, const float* __restrict__ conv_w,
    const float* __restrict__ conv_cb, const float* __restrict__ conv_a,
    f16* __restrict__ gT, float* __restrict__ wc1L, float* __restrict__ wc2L){
  __shared__ float zrow[2][256];
  __shared__ float cw[KC];
  __shared__ float ca[256];
  __shared__ float red[2][2];
  __shared__ float red2[2][2][2];
  int t = threadIdx.x, g = t >> 7, c = t & 127;
  int r = blockIdx.x*2 + g;
  if (t < KC) cw[t] = conv_w[t];
  ca[t] = conv_a[t];
  float zv0 = 0.f, zv1 = 0.f;
#pragma unroll
  for (int h = 0; h < 2; h++){
    const float* nr = num + ((size_t)h*NN + r)*D1;
    float inv = 1.f / den[h*NN + r];
    float e0 = eluf(nr[c]*inv);
    float e1 = eluf(nr[c + 128]*inv);
    float ss = e0*e0 + e1*e1;
#pragma unroll
    for (int o = 32; o > 0; o >>= 1) ss += __shfl_xor(ss, o);
    if ((t & 63) == 0) red[g][(t >> 6) & 1] = ss;
    __syncthreads();
    float invn = 1.f / fmaxf(sqrtf(red[g][0] + red[g][1]), 1e-12f);
    zv0 += e0*invn + head_b[h*D1 + c];
    zv1 += e1*invn + head_b[h*D1 + 128 + c];
    __syncthreads();
  }
  zrow[g][c]       = eluf(0.5f*zv0);
  zrow[g][c + 128] = eluf(0.5f*zv1);
  __syncthreads();
  float s = conv_cb[0];
  for (int k = 0; k < KC; k++) s += zrow[g][c + k]*cw[k];
  gT[(size_t)c*NN + r] = (f16)s;
  float p1 = s*ca[c], p2 = s*ca[128 + c];
#pragma unroll
  for (int o = 32; o > 0; o >>= 1){ p1 += __shfl_xor(p1, o); p2 += __shfl_xor(p2, o); }
  if ((t & 63) == 0){ red2[g][(t >> 6) & 1][0] = p1; red2[g][(t >> 6) & 1][1] = p2; }
  __syncthreads();
  if ((t & 127) == 0){
    wc1L[r] = (red2[g][0][0] + red2[g][1][0])*L2E;
    wc2L[r] = (red2[g][0][1] + red2[g][1][1])*L2E;
  }
}

// ---------------- A2: conv GAT aggregation (elu scores, m=0). i-tile 64, D=128, j-split 8 ----------------
__global__ __launch_bounds__(256) void k_agg_conv(
    const f16* __restrict__ gT, const unsigned* __restrict__ maskw,
    const float* __restrict__ wc1L, const float* __restrict__ wc2L,
    float* __restrict__ num, float* __restrict__ den){
  __shared__ f16 Hs[128*72];
  __shared__ f16 Ws[64*72];
  __shared__ float rowc[64];
  int i0 = blockIdx.x*64;
  int jbase = blockIdx.y*1024;
  int t = threadIdx.x, lane = t & 63, w = t >> 6;
  int rm = lane & 15, qm = (lane >> 4)*8;
  if (t < 64) rowc[t] = wc1L[i0 + t];
  __syncthreads();
  int si = t >> 2, sjq = (t & 3)*16;
  float ra = rowc[si];
  const unsigned* mrowp = maskw + (size_t)(i0 + si)*(NN/32);
  float rden = 0.f;
  f32x4 acc[4][2] = {};
  for (int j0 = 0; j0 < 1024; j0 += 64){
    int jg = jbase + j0;
#pragma unroll
    for (int p = 0; p < 4; p++){
      int idx = p*256 + t, dr = idx >> 3, cc = (idx & 7)*8;
      *(uint4*)&Hs[dr*72 + cc] = *(const uint4*)&gT[(size_t)dr*NN + jg + cc];
    }
    unsigned mb = mrowp[(jg + sjq) >> 5] >> (sjq & 31);
    float ca[16];
#pragma unroll
    for (int k = 0; k < 4; k++){
      float4 va = *(const float4*)&wc2L[jg + sjq + 4*k];
      ca[4*k]=va.x; ca[4*k+1]=va.y; ca[4*k+2]=va.z; ca[4*k+3]=va.w;
    }
    f16x8 wlo, whi;
    float dsum = 0.f;
#pragma unroll
    for (int q = 0; q < 16; q++){
      float sL = ra + ca[q];                   // s*log2e
      float t2 = EXP2(sL);                     // e^s
      float wv = sL > 0.f ? t2 : EXP2((t2 - 1.f)*L2E);  // exp(elu(s))
      wv = ((mb >> q) & 1u) ? wv : 0.f;
      dsum += wv;
      if (q < 8) wlo[q] = (f16)wv; else whi[q - 8] = (f16)wv;
    }
    *(f16x8*)&Ws[si*72 + sjq]     = wlo;
    *(f16x8*)&Ws[si*72 + sjq + 8] = whi;
    dsum += __shfl_xor(dsum, 1);
    dsum += __shfl_xor(dsum, 2);
    rden += dsum;
    __syncthreads();
    // wave w owns d-range w*32..w*32+31, all 64 i
#pragma unroll
    for (int ks = 0; ks < 2; ks++){
      f16x8 a[4], b[2];
#pragma unroll
      for (int mi = 0; mi < 4; mi++) a[mi] = *(const f16x8*)&Ws[(mi*16 + rm)*72 + ks*32 + qm];
#pragma unroll
      for (int fn = 0; fn < 2; fn++) b[fn] = *(const f16x8*)&Hs[(w*32 + fn*16 + rm)*72 + ks*32 + qm];
#pragma unroll
      for (int mi = 0; mi < 4; mi++)
#pragma unroll
        for (int fn = 0; fn < 2; fn++)
          acc[mi][fn] = __builtin_amdgcn_mfma_f32_16x16x32_f16(a[mi], b[fn], acc[mi][fn], 0, 0, 0);
    }
    __syncthreads();
  }
  if ((t & 3) == 0) atomicAdd(&den[i0 + si], rden);
  int quad = lane >> 4, cl = lane & 15;
#pragma unroll
  for (int mi = 0; mi < 4; mi++)
#pragma unroll
    for (int fn = 0; fn < 2; fn++){
      int rr = i0 + mi*16 + quad*4;
      int dc = w*32 + fn*16 + cl;
#pragma unroll
      for (int reg = 0; reg < 4; reg++)
        atomicAdd(&num[(size_t)(rr + reg)*D2 + dc], acc[mi][fn][reg]);
    }
}

// ---------------- E2: embed = l2norm(elu(num/den)) + conv_b ----------------
__global__ __launch_bounds__(256) void k_embed(
    const float* __restrict__ numc, const float* __restrict__ denc,
    const float* __restrict__ conv_b, float* __restrict__ embed){
  __shared__ float red[2][2];
  int t = threadIdx.x, g = t >> 7, c = t & 127;
  int r = blockIdx.x*2 + g;
  float e = eluf(numc[(size_t)r*D2 + c] / denc[r]);
  float ss = e*e;
#pragma unroll
  for (int o = 32; o > 0; o >>= 1) ss += __shfl_xor(ss, o);
  if ((t & 63) == 0) red[g][(t >> 6) & 1] = ss;
  __syncthreads();
  float invn = 1.f / fmaxf(sqrtf(red[g][0] + red[g][1]), 1e-12f);
  embed[(size_t)r*D2 + c] = e*invn + conv_b[c];
}

// ---------------- E3: two 128->128->64 elu MLPs, 32 rows/block, 4 rows/iter ----------------
__global__ __launch_bounds__(256) void k_mlp(
    const float* __restrict__ embed,
    const float* __restrict__ fw1, const float* __restrict__ fb1,
    const float* __restrict__ fw2, const float* __restrict__ fb2,
    const float* __restrict__ gw1, const float* __restrict__ gb1,
    const float* __restrict__ gw2, const float* __restrict__ gb2,
    float* __restrict__ tf, float* __restrict__ tg){
  const float* w1 = blockIdx.y ? gw1 : fw1;
  const float* b1 = blockIdx.y ? gb1 : fb1;
  const float* w2 = blockIdx.y ? gw2 : fw2;
  const float* b2 = blockIdx.y ? gb2 : fb2;
  float* out = blockIdx.y ? tg : tf;
  int t = threadIdx.x;
  int c = t & 127, kh = t >> 7;
  int o = t & 63, kh2 = t >> 6;
  float rw1[64];
#pragma unroll
  for (int i = 0; i < 64; i++) rw1[i] = w1[(kh*64 + i)*128 + c];
  float rw2[32];
#pragma unroll
  for (int i = 0; i < 32; i++) rw2[i] = w2[(kh2*32 + i)*64 + o];
  float bb1 = b1[c], bb2 = b2[o];
  __shared__ float erow[4][128];
  __shared__ float hidp[2][4][128];
  __shared__ float hid[4][128];
  __shared__ float outp[4][4][64];
  int r0 = blockIdx.x*32;
  for (int it = 0; it < 8; it++){
    int rbase = r0 + it*4;
    ((float2*)erow)[t] = ((const float2*)(embed + (size_t)rbase*128))[t];
    __syncthreads();
#pragma unroll
    for (int g = 0; g < 4; g++){
      float s = 0.f;
#pragma unroll
      for (int i = 0; i < 64; i++) s += erow[g][kh*64 + i]*rw1[i];
      hidp[kh][g][c] = s;
    }
    __syncthreads();
#pragma unroll
    for (int gg = 0; gg < 2; gg++){
      int g = kh + 2*gg;
      hid[g][c] = eluf(bb1 + hidp[0][g][c] + hidp[1][g][c]);
    }
    __syncthreads();
#pragma unroll
    for (int g = 0; g < 4; g++){
      float s = 0.f;
#pragma unroll
      for (int i = 0; i < 32; i++) s += hid[g][kh2*32 + i]*rw2[i];
      outp[kh2][g][o] = s;
    }
    __syncthreads();
    { int g = t >> 6;
      out[(size_t)(rbase + g)*64 + o] =
        eluf(bb2 + outp[0][g][o] + outp[1][g][o] + outp[2][g][o] + outp[3][g][o]); }
    __syncthreads();
  }
}

// ---------------- E4: pred = rowwise dot of gathered tf/tg (float4, 16 lanes/pair) ----------------
__global__ __launch_bounds__(256) void k_pred(
    const int* __restrict__ ts, const float4* __restrict__ tf4,
    const float4* __restrict__ tg4, float* __restrict__ out){
  int p = blockIdx.x*16 + (threadIdx.x >> 4);
  int l = threadIdx.x & 15;
  int i = ts[2*p], j = ts[2*p + 1];
  float4 a = tf4[(size_t)i*16 + l], b = tg4[(size_t)j*16 + l];
  float v = a.x*b.x + a.y*b.y + a.z*b.z + a.w*b.w;
  v += __shfl_xor(v, 1); v += __shfl_xor(v, 2);
  v += __shfl_xor(v, 4); v += __shfl_xor(v, 8);
  if (l == 0) out[p] = v;
}

// ---------------- workspace layout ----------------
#define OFF_MASK  ((size_t)0)
#define OFF_X16   ((size_t)8388608)
#define OFF_WT16  ((size_t)20971520)
#define OFF_HT16  ((size_t)21757952)
#define OFF_WH1   ((size_t)30146560)
#define OFF_WH2   ((size_t)30212096)
#define OFF_C1    ((size_t)30277632)
#define OFF_C2    ((size_t)30343168)
#define OFF_GMAX  ((size_t)30408704)
#define OFF_NUM1  ((size_t)30408960)
#define OFF_DEN1  ((size_t)47186176)
#define OFF_GT16  ((size_t)47251712)
#define OFF_WC1L  ((size_t)49348864)
#define OFF_WC2L  ((size_t)49381632)
#define OFF_NUMC  ((size_t)49414400)
#define OFF_DENC  ((size_t)53608704)
#define OFF_EMB   ((size_t)53641472)
#define OFF_TF    ((size_t)57835776)
#define OFF_TG    ((size_t)59932928)

extern "C" void kernel_launch(void* const* d_in, const int* in_sizes, int n_in,
                              void* d_out, int out_size, void* d_ws, size_t ws_size,
                              hipStream_t stream){
  const float* x      = (const float*)d_in[0];
  const int*   adj    = (const int*)d_in[1];
  const int*   ts     = (const int*)d_in[2];
  const float* head_W = (const float*)d_in[3];
  const float* head_a = (const float*)d_in[4];
  const float* head_b = (const float*)d_in[5];
  const float* conv_w = (const float*)d_in[6];
  const float* conv_cb= (const float*)d_in[7];
  const float* conv_a = (const float*)d_in[8];
  const float* conv_b = (const float*)d_in[9];
  const float* tf_w1  = (const float*)d_in[10];
  const float* tf_b1  = (const float*)d_in[11];
  const float* tf_w2  = (const float*)d_in[12];
  const float* tf_b2  = (const float*)d_in[13];
  const float* tg_w1  = (const float*)d_in[14];
  const float* tg_b1  = (const float*)d_in[15];
  const float* tg_w2  = (const float*)d_in[16];
  const float* tg_b2  = (const float*)d_in[17];
  float* outp = (float*)d_out;
  char* ws = (char*)d_ws;

  unsigned* maskw = (unsigned*)(ws + OFF_MASK);
  f16*   x16   = (f16*)(ws + OFF_X16);
  f16*   Wt16  = (f16*)(ws + OFF_WT16);
  f16*   hT16  = (f16*)(ws + OFF_HT16);
  float* wh1   = (float*)(ws + OFF_WH1);
  float* wh2   = (float*)(ws + OFF_WH2);
  float* c1    = (float*)(ws + OFF_C1);
  float* c2    = (float*)(ws + OFF_C2);
  unsigned* gmax = (unsigned*)(ws + OFF_GMAX);
  float* num1  = (float*)(ws + OFF_NUM1);
  float* den1  = (float*)(ws + OFF_DEN1);
  f16*   gT16  = (f16*)(ws + OFF_GT16);
  float* wc1L  = (float*)(ws + OFF_WC1L);
  float* wc2L  = (float*)(ws + OFF_WC2L);
  float* numc  = (float*)(ws + OFF_NUMC);
  float* denc  = (float*)(ws + OFF_DENC);
  float* emb   = (float*)(ws + OFF_EMB);
  float* tf    = (float*)(ws + OFF_TF);
  float* tg    = (float*)(ws + OFF_TG);

  // zero atomic accumulators (ws is poisoned before every call)
  hipMemsetAsync(wh1, 0, 2*2*NN*sizeof(float), stream);            // wh1+wh2
  hipMemsetAsync(gmax, 0, 2*sizeof(unsigned), stream);
  hipMemsetAsync(num1, 0, (size_t)2*NN*D1*sizeof(float) + 2*NN*sizeof(float), stream); // num1+den1
  hipMemsetAsync(numc, 0, (size_t)NN*D2*sizeof(float) + NN*sizeof(float), stream);     // numc+denc

  k_pack   <<<NN*NN/1024, 256, 0, stream>>>((const int4*)adj, maskw);
  k_cast_x <<<(NN*IND)/(256*4), 256, 0, stream>>>(x, x16);
  k_wt     <<<DT, 256, 0, stream>>>(head_W, Wt16);
  k_gemm_h <<<dim3(NN/64, DT/128), 256, 0, stream>>>(x16, Wt16, head_a, hT16, wh1, wh2);
  k_gmax   <<<dim3(NN/256, 2), 256, 0, stream>>>(wh2, gmax);
  k_colterms<<<(2*NN)/256, 256, 0, stream>>>(wh2, c1, c2);
  k_agg_head<<<dim3(NN/64, 2, 2), 256, 0, stream>>>(hT16, maskw, wh1, c1, c2, gmax, num1, den1);
  k_merge_conv<<<NN/2, 256, 0, stream>>>(num1, den1, head_b, conv_w, conv_cb, conv_a, gT16, wc1L, wc2L);
  k_agg_conv<<<dim3(NN/64, 8), 256, 0, stream>>>(gT16, maskw, wc1L, wc2L, numc, denc);
  k_embed  <<<NN/2, 256, 0, stream>>>(numc, denc, conv_b, emb);
  k_mlp    <<<dim3(NN/32, 2), 256, 0, stream>>>(emb, tf_w1, tf_b1, tf_w2, tf_b2,
                                                tg_w1, tg_b1, tg_w2, tg_b2, tf, tg);
  k_pred   <<<EPAIRS/16, 256, 0, stream>>>(ts, (const float4*)tf, (const float4*)tg, outp);
}